// Round 7
// baseline (15862.735 us; speedup 1.0000x reference)
//
#include <hip/hip_runtime.h>
#include <cstdint>
#include <cstddef>

#define NBATCH 2
#define NSAMPLE 32

// ---------------------------------------------------------------------------
// transpose xyz [B,N,3] -> xyzT [B,3,N]  (stage-0 features)
// ---------------------------------------------------------------------------
__global__ void xyzT_kernel(const float* __restrict__ xyz, float* __restrict__ xyzT, int N)
{
    int t = blockIdx.x * blockDim.x + threadIdx.x;
    int total = NBATCH * N;
    if (t >= total) return;
    int b = t / N, n = t - b * N;
    const float* p = xyz + ((size_t)b * N + n) * 3;
    float* o = xyzT + (size_t)b * 3 * N + n;
    o[0]            = p[0];
    o[(size_t)N]    = p[1];
    o[2 * (size_t)N] = p[2];
}

__device__ inline unsigned p1b2(unsigned x)   // spread 10 bits -> every 3rd bit
{
    x &= 0x3FFu;
    x = (x | (x << 16)) & 0x030000FFu;
    x = (x | (x << 8))  & 0x0300F00Fu;
    x = (x | (x << 4))  & 0x030C30C3u;
    x = (x | (x << 2))  & 0x09249249u;
    return x;
}

// ---------------------------------------------------------------------------
// cluster_build<N>: per batch -- Morton-sort the N support points, emit
// permuted planar coords gx/gy/gz, original indices gidx, and per-64-point
// cluster stats (centroid, inflated radius covering all cluster points).
// ---------------------------------------------------------------------------
template<int N>
__global__ __launch_bounds__(512)
void cluster_build(const float* __restrict__ xyz,
                   float* __restrict__ gx, float* __restrict__ gy,
                   float* __restrict__ gz, unsigned* __restrict__ gidx,
                   float4* __restrict__ gstats)
{
    constexpr int BT = 512, G = N / 64;
    __shared__ unsigned long long sk[N];
    __shared__ float s_red[8][6];
    __shared__ float s_bb[6];

    const int b = blockIdx.x;
    const int t = threadIdx.x;
    const int lane = t & 63, w = t >> 6;
    const float* xb = xyz + (size_t)b * N * 3;
    gx += (size_t)b * N; gy += (size_t)b * N; gz += (size_t)b * N;
    gidx += (size_t)b * N; gstats += (size_t)b * G;

    // ---- bbox ----
    float mnx = 1e30f, mny = 1e30f, mnz = 1e30f;
    float mxx = -1e30f, mxy = -1e30f, mxz = -1e30f;
    for (int p = t; p < N; p += BT) {
        float x = xb[3 * p], y = xb[3 * p + 1], z = xb[3 * p + 2];
        mnx = fminf(mnx, x); mxx = fmaxf(mxx, x);
        mny = fminf(mny, y); mxy = fmaxf(mxy, y);
        mnz = fminf(mnz, z); mxz = fmaxf(mxz, z);
    }
#pragma unroll
    for (int m = 1; m < 64; m <<= 1) {
        mnx = fminf(mnx, __shfl_xor(mnx, m)); mxx = fmaxf(mxx, __shfl_xor(mxx, m));
        mny = fminf(mny, __shfl_xor(mny, m)); mxy = fmaxf(mxy, __shfl_xor(mxy, m));
        mnz = fminf(mnz, __shfl_xor(mnz, m)); mxz = fmaxf(mxz, __shfl_xor(mxz, m));
    }
    if (lane == 0) {
        s_red[w][0] = mnx; s_red[w][1] = mny; s_red[w][2] = mnz;
        s_red[w][3] = mxx; s_red[w][4] = mxy; s_red[w][5] = mxz;
    }
    __syncthreads();
    if (t == 0) {
        for (int c = 0; c < 3; ++c) {
            float mn = s_red[0][c], mx = s_red[0][3 + c];
            for (int i = 1; i < 8; ++i) {
                mn = fminf(mn, s_red[i][c]);
                mx = fmaxf(mx, s_red[i][3 + c]);
            }
            s_bb[c] = mn; s_bb[3 + c] = mx;
        }
    }
    __syncthreads();
    const float bx = s_bb[0], by = s_bb[1], bz = s_bb[2];
    const float sx = 1024.0f / fmaxf(s_bb[3] - bx, 1e-9f);
    const float sy = 1024.0f / fmaxf(s_bb[4] - by, 1e-9f);
    const float sz = 1024.0f / fmaxf(s_bb[5] - bz, 1e-9f);

    // ---- morton keys ----
    for (int p = t; p < N; p += BT) {
        unsigned cx = min(1023, (int)((xb[3 * p] - bx) * sx));
        unsigned cy = min(1023, (int)((xb[3 * p + 1] - by) * sy));
        unsigned cz = min(1023, (int)((xb[3 * p + 2] - bz) * sz));
        unsigned m = (p1b2(cz) << 2) | (p1b2(cy) << 1) | p1b2(cx);
        sk[p] = ((unsigned long long)m << 14) | (unsigned)p;
    }
    __syncthreads();

    // ---- bitonic sort (unique keys: idx in low bits) ----
    for (int k = 2; k <= N; k <<= 1) {
        for (int jj = k >> 1; jj > 0; jj >>= 1) {
            for (int q = t; q < N / 2; q += BT) {
                int i = ((q & ~(jj - 1)) << 1) | (q & (jj - 1));
                int pr = i | jj;
                unsigned long long a = sk[i], c = sk[pr];
                bool asc = ((i & k) == 0);
                if ((a > c) == asc) { sk[i] = c; sk[pr] = a; }
            }
            __syncthreads();
        }
    }

    // ---- permuted outputs ----
    for (int s = t; s < N; s += BT) {
        unsigned p = (unsigned)(sk[s] & 0x3FFFu);
        gidx[s] = p;
        gx[s] = xb[3 * p];
        gy[s] = xb[3 * p + 1];
        gz[s] = xb[3 * p + 2];
    }
    __threadfence_block();
    __syncthreads();

    // ---- cluster stats: centroid + inflated radius ----
    for (int c = w; c < G; c += 8) {
        int slot = c * 64 + lane;
        float x = gx[slot], y = gy[slot], z = gz[slot];
        float sxx = x, syy = y, szz = z;
#pragma unroll
        for (int m = 1; m < 64; m <<= 1) {
            sxx += __shfl_xor(sxx, m);
            syy += __shfl_xor(syy, m);
            szz += __shfl_xor(szz, m);
        }
        float ccx = sxx * (1.0f / 64.0f), ccy = syy * (1.0f / 64.0f), ccz = szz * (1.0f / 64.0f);
        float dx = x - ccx, dy = y - ccy, dz = z - ccz;
        float d2 = dx * dx + dy * dy + dz * dz;
#pragma unroll
        for (int m = 1; m < 64; m <<= 1) d2 = fmaxf(d2, __shfl_xor(d2, m));
        if (lane == 0)
            gstats[c] = make_float4(ccx, ccy, ccz, sqrtf(d2) * 1.00001f + 1e-6f);
    }
}

// ---------------------------------------------------------------------------
// fps_cluster<N,BT>: exact FPS with cluster pruning, round-7 structure.
//  - wave w owns clusters c = j*NW + w (round-robin: spatially-local flagged
//    clusters spread across waves -> balanced barrier arrival)
//  - stats & cluster-key tables stored PERMUTED ([w*OWN+j]) -> bound-test
//    LDS reads are contiguous, conflict-free (round-6: 3.8M conflicts)
//  - per-cluster key (dd_max_bits<<32 | ~orig_idx) is refreshed by a 64-lane
//    butterfly ONLY when the cluster is flagged; skipped clusters' stale keys
//    are exactly current (their dd didn't change).  Key high word doubles as
//    the prune bound cmax.
//  - skip exactness: cluster skipped iff (sqrt(d2c)*(1-1e-5)-rad)^2*(1-2e-5)
//    >= cmax  =>  every point's reference distance >= its dd  =>  fp32 min
//    update is the identity.  Margins (1e-5) >> fp32 arithmetic slop.
//  - exact jnp rounding in the dd update (plain mul/add, fminf); global
//    argmax ties -> lowest ORIGINAL index via ~idx in the key.
//  - one __syncthreads per step; winner coords re-read from original xyz
//    (exact bits, broadcast load).
// ---------------------------------------------------------------------------
template<int N, int BT>
__global__ __launch_bounds__(BT)
void fps_cluster(const float* __restrict__ xyz,
                 const float* __restrict__ gx, const float* __restrict__ gy,
                 const float* __restrict__ gz, const unsigned* __restrict__ gidx,
                 const float4* __restrict__ gstats,
                 int npoint, float* __restrict__ query)
{
    constexpr int G = N / 64, NW = BT / 64, OWN = G / NW;
    __shared__ float s_xy[2 * N];
    __shared__ float4 s_stp[G];                  // permuted stats
    __shared__ unsigned long long s_ck[G];       // permuted cluster keys
    __shared__ unsigned long long s_wkey[2][NW];

    const int b = blockIdx.x;
    const int t = threadIdx.x;
    const int lane = t & 63, w = t >> 6;
    const float* xb = xyz + (size_t)b * N * 3;
    gx += (size_t)b * N; gy += (size_t)b * N; gz += (size_t)b * N;
    gidx += (size_t)b * N;
    gstats += (size_t)b * G;

    float zr[OWN], dd[OWN];
    unsigned pidx[OWN];
#pragma unroll
    for (int j = 0; j < OWN; ++j) {
        int s = (j * NW + w) * 64 + lane;        // round-robin ownership
        s_xy[2 * s]     = gx[s];
        s_xy[2 * s + 1] = gy[s];
        zr[j]   = gz[s];
        pidx[j] = gidx[s];
        dd[j]   = 1e10f;
    }
    for (int i = t; i < G; i += BT) {
        s_stp[i] = gstats[(i % OWN) * NW + i / OWN];
        s_ck[i]  = ((unsigned long long)__float_as_uint(1e10f) << 32);
    }
    __syncthreads();

    float cx = xb[0], cy = xb[1], cz = xb[2];
    if (t == 0) {
        float* q = query + (size_t)b * npoint * 3;
        q[0] = cx; q[1] = cy; q[2] = cz;
    }

    for (int step = 1; step < npoint; ++step) {
        const int buf = step & 1;
        // ---- bound test: lane j tests own cluster j (contiguous LDS) ----
        bool f = false;
        if (lane < OWN) {
            const float4 cs = s_stp[w * OWN + lane];
            float cmax = __uint_as_float((unsigned)(s_ck[w * OWN + lane] >> 32));
            float dx = cs.x - cx, dy = cs.y - cy, dz = cs.z - cz;
            float d2c = dx * dx + dy * dy + dz * dz;
            float Dlb = sqrtf(d2c) * 0.99999f - cs.w;
            f = !(Dlb > 0.0f && Dlb * Dlb * 0.99998f >= cmax);
        }
        const unsigned long long fm = __ballot(f);
        // ---- update flagged clusters; refresh their key via butterfly ----
#pragma unroll
        for (int j = 0; j < OWN; ++j) {
            if ((fm >> j) & 1ull) {
                int s = (j * NW + w) * 64 + lane;
                const float2 xy = *(const float2*)&s_xy[2 * s];
                float dx = xy.x - cx, dy = xy.y - cy, dz = zr[j] - cz;
                float d = __fmul_rn(dx, dx);
                d = __fadd_rn(d, __fmul_rn(dy, dy));
                d = __fadd_rn(d, __fmul_rn(dz, dz));
                float nd = fminf(dd[j], d);
                dd[j] = nd;
                unsigned long long k =
                    ((unsigned long long)__float_as_uint(nd) << 32) | (unsigned)(~pidx[j]);
#pragma unroll
                for (int m = 1; m < 64; m <<= 1) {
                    unsigned long long o = __shfl_xor(k, m);
                    k = (o > k) ? o : k;
                }
                if (lane == 0) s_ck[w * OWN + j] = k;
            }
        }
        // ---- wave candidate: max over own OWN cluster keys ----
        unsigned long long bk = s_ck[w * OWN + (lane & (OWN - 1))];
#pragma unroll
        for (int m = 1; m < OWN; m <<= 1) {
            unsigned long long o = __shfl_xor(bk, m);
            bk = (o > bk) ? o : bk;
        }
        if (lane == 0) s_wkey[buf][w] = bk;
        __syncthreads();
        // ---- block winner ----
        unsigned long long gk = s_wkey[buf][lane & (NW - 1)];
#pragma unroll
        for (int m = 1; m < NW; m <<= 1) {
            unsigned long long o = __shfl_xor(gk, m);
            gk = (o > gk) ? o : gk;
        }
        unsigned widx = ~(unsigned)gk;            // original index, block-uniform
        const float* wp = xb + (size_t)widx * 3;
        cx = wp[0]; cy = wp[1]; cz = wp[2];       // broadcast, exact original bits
        if (t == 0) {
            float* q = query + ((size_t)b * npoint + step) * 3;
            q[0] = cx; q[1] = cy; q[2] = cz;
        }
    }
}

// ---------------------------------------------------------------------------
// FPS brute force (stages 2-3, small N): coords in LDS, dd in registers.
// ---------------------------------------------------------------------------
template<int PPT, int BT, int WPE>
__global__ __launch_bounds__(BT)
__attribute__((amdgpu_waves_per_eu(WPE, WPE)))
void fps_gen(const float* __restrict__ xyz, int npoint, float* __restrict__ query)
{
    const int N = PPT * BT;
    constexpr int NW = BT / 64;
    __shared__ float4 s_p[PPT * BT];
    __shared__ unsigned long long s_wkey[2][NW];

    const int b = blockIdx.x;
    const int t = threadIdx.x;
    const int lane = t & 63;
    const int wid  = t >> 6;
    const float* xb = xyz + (size_t)b * N * 3;

    float dd[PPT];
#pragma unroll
    for (int i = 0; i < PPT; ++i) {
        int p = i * BT + t;
        const float* pp = xb + (size_t)p * 3;
        s_p[p] = make_float4(pp[0], pp[1], pp[2], 0.0f);
        dd[i] = 1e10f;
    }

    float cx = xb[0], cy = xb[1], cz = xb[2];
    if (t == 0) {
        float* q = query + (size_t)b * npoint * 3;
        q[0] = cx; q[1] = cy; q[2] = cz;
    }

    for (int step = 1; step < npoint; ++step) {
        const int buf = step & 1;
        float bd = -1.0f;
        int bslot = 0;
#pragma unroll
        for (int i = 0; i < PPT; ++i) {
            const float4 v = s_p[i * BT + t];
            float dx = v.x - cx, dy = v.y - cy, dz = v.z - cz;
            float d = __fmul_rn(dx, dx);
            d = __fadd_rn(d, __fmul_rn(dy, dy));
            d = __fadd_rn(d, __fmul_rn(dz, dz));
            float nd = fminf(dd[i], d);
            dd[i] = nd;
            bool g = nd > bd;
            bd    = g ? nd : bd;
            bslot = g ? i : bslot;
        }
        int bidx = bslot * BT + t;
        unsigned long long key =
            ((unsigned long long)__float_as_uint(bd) << 32) | (unsigned int)(~bidx);
#pragma unroll
        for (int m = 1; m < 64; m <<= 1) {
            unsigned long long o = __shfl_xor(key, m);
            key = (o > key) ? o : key;
        }
        if (lane == 0) s_wkey[buf][wid] = key;
        __syncthreads();
        unsigned long long v[NW];
#pragma unroll
        for (int w = 0; w < NW; ++w) v[w] = s_wkey[buf][w];
#pragma unroll
        for (int s = NW / 2; s > 0; s >>= 1)
#pragma unroll
            for (int w = 0; w < NW / 2; ++w)
                if (w < s) v[w] = (v[w + s] > v[w]) ? v[w + s] : v[w];
        unsigned int widx = ~(unsigned int)v[0];
        const float* wp = xb + (size_t)widx * 3;
        cx = wp[0]; cy = wp[1]; cz = wp[2];
        if (t == 0) {
            float* q = query + ((size_t)b * npoint + step) * 3;
            q[0] = cx; q[1] = cy; q[2] = cz;
        }
    }
}

// ---------------------------------------------------------------------------
// Ball query: one wave per query point, exact fp32 rounding (no fma).
// ---------------------------------------------------------------------------
__global__ void ballquery_kernel(const float* __restrict__ support,
                                 const float* __restrict__ query,
                                 int N, int Q, float r2,
                                 int* __restrict__ nbr)
{
    int gw   = (blockIdx.x * blockDim.x + threadIdx.x) >> 6;
    int lane = threadIdx.x & 63;
    if (gw >= NBATCH * Q) return;
    int b = gw / Q;
    int q = gw - b * Q;

    const float* sb = support + (size_t)b * N * 3;
    const float* qp = query + ((size_t)b * Q + q) * 3;
    float qx = qp[0], qy = qp[1], qz = qp[2];
    int* out = nbr + ((size_t)b * Q + q) * NSAMPLE;

    int cnt = 0, first = 0;
    for (int base = 0; base < N; base += 64) {
        int j = base + lane;
        float dx = __fsub_rn(sb[j * 3 + 0], qx);
        float dy = __fsub_rn(sb[j * 3 + 1], qy);
        float dz = __fsub_rn(sb[j * 3 + 2], qz);
        float d2 = __fmul_rn(dx, dx);
        d2 = __fadd_rn(d2, __fmul_rn(dy, dy));
        d2 = __fadd_rn(d2, __fmul_rn(dz, dz));
        bool inr = d2 < r2;
        unsigned long long mask = __ballot(inr);
        if (mask) {
            if (cnt == 0) first = base + (int)__builtin_ctzll(mask);
            if (inr) {
                int pos = cnt + (int)__popcll(mask & ((1ull << lane) - 1ull));
                if (pos < NSAMPLE) out[pos] = j;
            }
            cnt += (int)__popcll(mask);
            if (cnt >= NSAMPLE) break;
        }
    }
    for (int pos = cnt + lane; pos < NSAMPLE; pos += 64) out[pos] = first;
}

// ---------------------------------------------------------------------------
// Build F0 [3+C, Q*32] for one batch.
// ---------------------------------------------------------------------------
__global__ void gather_kernel(const float* __restrict__ support,
                              const float* __restrict__ query,
                              const int* __restrict__ nbr,
                              const float* __restrict__ feats,
                              int N, int Q, int C, int b,
                              float* __restrict__ F0)
{
    int n = blockIdx.x * blockDim.x + threadIdx.x;
    int Nn = Q * NSAMPLE;
    if (n >= Nn) return;
    int q = n >> 5, s = n & 31;
    int j = nbr[((size_t)b * Q + q) * NSAMPLE + s];
    const float* sp = support + ((size_t)b * N + j) * 3;
    const float* qp = query + ((size_t)b * Q + q) * 3;
    size_t NnS = (size_t)Nn;
    F0[n]           = sp[0] - qp[0];
    F0[NnS + n]     = sp[1] - qp[1];
    F0[2 * NnS + n] = sp[2] - qp[2];
    const float* fb = feats + (size_t)b * C * N;
    float* Fo = F0 + 3 * NnS + n;
    for (int c = 0; c < C; ++c) Fo[(size_t)c * NnS] = fb[(size_t)c * N + j];
}

// ---------------------------------------------------------------------------
// fp32 tiled GEMM with fused ReLU (and max-pool epilogue when POOL).
// ---------------------------------------------------------------------------
template<bool POOL>
__global__ __launch_bounds__(256)
void gemm_relu(const float* __restrict__ W, const float* __restrict__ bias,
               const float* __restrict__ F, float* __restrict__ Out,
               int M, int K, int Nn, int b)
{
    __shared__ float Ws[16][64];
    __shared__ float Fs[16][68];

    const int n0 = blockIdx.x * 64;
    const int m0 = blockIdx.y * 64;
    const int tid = threadIdx.x;
    const int tx = tid & 15, ty = tid >> 4;

    float acc[4][4] = {};

    const int wm = tid >> 2;
    const int wk = (tid & 3) * 4;
    const int fk = tid >> 4;
    const int fn = (tid & 15) * 4;

    for (int k0 = 0; k0 < K; k0 += 16) {
#pragma unroll
        for (int j = 0; j < 4; ++j) {
            int kk = wk + j;
            int kg = k0 + kk;
            Ws[kk][wm] = (kg < K) ? W[(size_t)(m0 + wm) * K + kg] : 0.0f;
        }
        {
            int kg = k0 + fk;
            float4 v = make_float4(0.f, 0.f, 0.f, 0.f);
            if (kg < K) v = *(const float4*)(F + (size_t)kg * Nn + n0 + fn);
            *(float4*)&Fs[fk][fn] = v;
        }
        __syncthreads();
#pragma unroll
        for (int kk = 0; kk < 16; ++kk) {
            float av[4], bv[4];
            *(float4*)av = *(const float4*)&Ws[kk][ty * 4];
            *(float4*)bv = *(const float4*)&Fs[kk][tx * 4];
#pragma unroll
            for (int i = 0; i < 4; ++i)
#pragma unroll
                for (int j = 0; j < 4; ++j)
                    acc[i][j] = fmaf(av[i], bv[j], acc[i][j]);
        }
        __syncthreads();
    }

    if constexpr (!POOL) {
#pragma unroll
        for (int i = 0; i < 4; ++i) {
            int m = m0 + ty * 4 + i;
            float bvs = bias[m];
            float4 r;
            r.x = fmaxf(acc[i][0] + bvs, 0.0f);
            r.y = fmaxf(acc[i][1] + bvs, 0.0f);
            r.z = fmaxf(acc[i][2] + bvs, 0.0f);
            r.w = fmaxf(acc[i][3] + bvs, 0.0f);
            *(float4*)(Out + (size_t)m * Nn + n0 + tx * 4) = r;
        }
    } else {
        __shared__ float Cs[64][65];
#pragma unroll
        for (int i = 0; i < 4; ++i) {
            int mr = ty * 4 + i;
            float bvs = bias[m0 + mr];
#pragma unroll
            for (int j = 0; j < 4; ++j)
                Cs[mr][tx * 4 + j] = fmaxf(acc[i][j] + bvs, 0.0f);
        }
        __syncthreads();
        if (tid < 128) {
            int r = tid >> 1, g = tid & 1;
            float mx = Cs[r][g * 32];
            for (int c = 1; c < 32; ++c) mx = fmaxf(mx, Cs[r][g * 32 + c]);
            int Qn = Nn >> 5;
            Out[((size_t)b * M + m0 + r) * Qn + (n0 >> 5) + g] = mx;
        }
    }
}

// ---------------------------------------------------------------------------
extern "C" void kernel_launch(void* const* d_in, const int* in_sizes, int n_in,
                              void* d_out, int out_size, void* d_ws, size_t ws_size,
                              hipStream_t stream)
{
    (void)in_sizes; (void)n_in; (void)out_size; (void)ws_size;
    const float* xyz = (const float*)d_in[0];
    const float* W[4][3]; const float* Bi[4][3];
    for (int k = 0; k < 4; ++k)
        for (int l = 0; l < 3; ++l) {
            W[k][l]  = (const float*)d_in[1 + k * 6 + l * 2];
            Bi[k][l] = (const float*)d_in[2 + k * 6 + l * 2];
        }
    float* out = (float*)d_out;

    uintptr_t cur = (uintptr_t)d_ws;
    auto alloc = [&](size_t bytes) -> void* {
        void* p = (void*)cur;
        cur += (bytes + 255) & ~(size_t)255;
        return p;
    };
    float* xyzT = (float*)alloc((size_t)NBATCH * 3 * 16384 * sizeof(float));
    float* qA   = (float*)alloc((size_t)NBATCH * 4096 * 3 * sizeof(float));
    float* qB   = (float*)alloc((size_t)NBATCH * 4096 * 3 * sizeof(float));
    int*   nbr  = (int*)  alloc((size_t)NBATCH * 4096 * NSAMPLE * sizeof(int));
    float* f0   = (float*)alloc((size_t)NBATCH * 128 * 4096 * sizeof(float));
    float* f1   = (float*)alloc((size_t)NBATCH * 256 * 1024 * sizeof(float));
    float* f2   = (float*)alloc((size_t)NBATCH * 512 * 256 * sizeof(float));
    float* X = (float*)alloc((size_t)8388608 * sizeof(float));
    float* Y = (float*)alloc((size_t)8388608 * sizeof(float));
    // cluster-FPS buffers (stage 0: N=16384, stage 1: N=4096)
    float*    c0x = (float*)   alloc((size_t)NBATCH * 16384 * sizeof(float));
    float*    c0y = (float*)   alloc((size_t)NBATCH * 16384 * sizeof(float));
    float*    c0z = (float*)   alloc((size_t)NBATCH * 16384 * sizeof(float));
    unsigned* c0i = (unsigned*)alloc((size_t)NBATCH * 16384 * sizeof(unsigned));
    float4*   c0s = (float4*)  alloc((size_t)NBATCH * 256 * sizeof(float4));
    float*    c1x = (float*)   alloc((size_t)NBATCH * 4096 * sizeof(float));
    float*    c1y = (float*)   alloc((size_t)NBATCH * 4096 * sizeof(float));
    float*    c1z = (float*)   alloc((size_t)NBATCH * 4096 * sizeof(float));
    unsigned* c1i = (unsigned*)alloc((size_t)NBATCH * 4096 * sizeof(unsigned));
    float4*   c1s = (float4*)  alloc((size_t)NBATCH * 64 * sizeof(float4));

    xyzT_kernel<<<(NBATCH * 16384 + 255) / 256, 256, 0, stream>>>(xyz, xyzT, 16384);

    struct StageP { int N, Q, Cprev, c1, c2, c3; double r; };
    const StageP st[4] = {
        {16384, 4096,   3,   64,  64,  128, 0.1},
        { 4096, 1024, 128,  128, 128,  256, 0.2},
        { 1024,  256, 256,  256, 256,  512, 0.4},
        {  256,   64, 512,  512, 512, 1024, 0.8},
    };
    const float* support   = xyz;
    const float* featsPrev = xyzT;
    float* qbuf[2]     = {qA, qB};
    float* featsOut[4] = {f0, f1, f2, out};

    for (int k = 0; k < 4; ++k) {
        const StageP& s = st[k];
        float* qcur = qbuf[k & 1];
        if (k == 0) {
            cluster_build<16384><<<NBATCH, 512, 0, stream>>>(support, c0x, c0y, c0z, c0i, c0s);
            fps_cluster<16384, 1024><<<NBATCH, 1024, 0, stream>>>(
                support, c0x, c0y, c0z, c0i, c0s, s.Q, qcur);
        } else if (k == 1) {
            cluster_build<4096><<<NBATCH, 512, 0, stream>>>(support, c1x, c1y, c1z, c1i, c1s);
            fps_cluster<4096, 512><<<NBATCH, 512, 0, stream>>>(
                support, c1x, c1y, c1z, c1i, c1s, s.Q, qcur);
        } else if (k == 2) {
            fps_gen<2, 512, 2><<<NBATCH, 512, 0, stream>>>(support, s.Q, qcur);
        } else {
            fps_gen<1, 256, 1><<<NBATCH, 256, 0, stream>>>(support, s.Q, qcur);
        }

        float r2 = (float)(s.r * s.r);
        ballquery_kernel<<<(NBATCH * s.Q) / 4, 256, 0, stream>>>(support, qcur, s.N, s.Q, r2, nbr);

        int K0 = 3 + s.Cprev;
        int Nn = s.Q * NSAMPLE;
        for (int b = 0; b < NBATCH; ++b) {
            gather_kernel<<<(Nn + 255) / 256, 256, 0, stream>>>(
                support, qcur, nbr, featsPrev, s.N, s.Q, s.Cprev, b, X);
            gemm_relu<false><<<dim3(Nn / 64, s.c1 / 64, 1), 256, 0, stream>>>(
                W[k][0], Bi[k][0], X, Y, s.c1, K0, Nn, 0);
            gemm_relu<false><<<dim3(Nn / 64, s.c2 / 64, 1), 256, 0, stream>>>(
                W[k][1], Bi[k][1], Y, X, s.c2, s.c1, Nn, 0);
            gemm_relu<true><<<dim3(Nn / 64, s.c3 / 64, 1), 256, 0, stream>>>(
                W[k][2], Bi[k][2], X, featsOut[k], s.c3, s.c2, Nn, b);
        }
        support   = qcur;
        featsPrev = featsOut[k];
    }
}

// Round 8
// 10058.765 us; speedup vs baseline: 1.5770x; 1.5770x over previous
//
#include <hip/hip_runtime.h>
#include <cstdint>
#include <cstddef>

#define NBATCH 2
#define NSAMPLE 32

// ---------------------------------------------------------------------------
// transpose xyz [B,N,3] -> xyzT [B,3,N]  (stage-0 features)
// ---------------------------------------------------------------------------
__global__ void xyzT_kernel(const float* __restrict__ xyz, float* __restrict__ xyzT, int N)
{
    int t = blockIdx.x * blockDim.x + threadIdx.x;
    int total = NBATCH * N;
    if (t >= total) return;
    int b = t / N, n = t - b * N;
    const float* p = xyz + ((size_t)b * N + n) * 3;
    float* o = xyzT + (size_t)b * 3 * N + n;
    o[0]            = p[0];
    o[(size_t)N]    = p[1];
    o[2 * (size_t)N] = p[2];
}

__device__ inline unsigned p1b2(unsigned x)   // spread 10 bits -> every 3rd bit
{
    x &= 0x3FFu;
    x = (x | (x << 16)) & 0x030000FFu;
    x = (x | (x << 8))  & 0x0300F00Fu;
    x = (x | (x << 4))  & 0x030C30C3u;
    x = (x | (x << 2))  & 0x09249249u;
    return x;
}

// ---------------------------------------------------------------------------
// cluster_build<N>: Morton-sort the N support points; emit permuted planar
// coords gx/gy/gz, original indices gidx, and per-16-POINT cluster stats
// (centroid, inflated radius).  G = N/16 clusters.
// ---------------------------------------------------------------------------
template<int N>
__global__ __launch_bounds__(512)
void cluster_build(const float* __restrict__ xyz,
                   float* __restrict__ gx, float* __restrict__ gy,
                   float* __restrict__ gz, unsigned* __restrict__ gidx,
                   float4* __restrict__ gstats)
{
    constexpr int BT = 512, G = N / 16;
    __shared__ unsigned long long sk[N];
    __shared__ float s_red[8][6];
    __shared__ float s_bb[6];

    const int b = blockIdx.x;
    const int t = threadIdx.x;
    const int lane = t & 63, w = t >> 6;
    const float* xb = xyz + (size_t)b * N * 3;
    gx += (size_t)b * N; gy += (size_t)b * N; gz += (size_t)b * N;
    gidx += (size_t)b * N; gstats += (size_t)b * G;

    // ---- bbox ----
    float mnx = 1e30f, mny = 1e30f, mnz = 1e30f;
    float mxx = -1e30f, mxy = -1e30f, mxz = -1e30f;
    for (int p = t; p < N; p += BT) {
        float x = xb[3 * p], y = xb[3 * p + 1], z = xb[3 * p + 2];
        mnx = fminf(mnx, x); mxx = fmaxf(mxx, x);
        mny = fminf(mny, y); mxy = fmaxf(mxy, y);
        mnz = fminf(mnz, z); mxz = fmaxf(mxz, z);
    }
#pragma unroll
    for (int m = 1; m < 64; m <<= 1) {
        mnx = fminf(mnx, __shfl_xor(mnx, m)); mxx = fmaxf(mxx, __shfl_xor(mxx, m));
        mny = fminf(mny, __shfl_xor(mny, m)); mxy = fmaxf(mxy, __shfl_xor(mxy, m));
        mnz = fminf(mnz, __shfl_xor(mnz, m)); mxz = fmaxf(mxz, __shfl_xor(mxz, m));
    }
    if (lane == 0) {
        s_red[w][0] = mnx; s_red[w][1] = mny; s_red[w][2] = mnz;
        s_red[w][3] = mxx; s_red[w][4] = mxy; s_red[w][5] = mxz;
    }
    __syncthreads();
    if (t == 0) {
        for (int c = 0; c < 3; ++c) {
            float mn = s_red[0][c], mx = s_red[0][3 + c];
            for (int i = 1; i < 8; ++i) {
                mn = fminf(mn, s_red[i][c]);
                mx = fmaxf(mx, s_red[i][3 + c]);
            }
            s_bb[c] = mn; s_bb[3 + c] = mx;
        }
    }
    __syncthreads();
    const float bx = s_bb[0], by = s_bb[1], bz = s_bb[2];
    const float sx = 1024.0f / fmaxf(s_bb[3] - bx, 1e-9f);
    const float sy = 1024.0f / fmaxf(s_bb[4] - by, 1e-9f);
    const float sz = 1024.0f / fmaxf(s_bb[5] - bz, 1e-9f);

    // ---- morton keys ----
    for (int p = t; p < N; p += BT) {
        unsigned cx = min(1023, (int)((xb[3 * p] - bx) * sx));
        unsigned cy = min(1023, (int)((xb[3 * p + 1] - by) * sy));
        unsigned cz = min(1023, (int)((xb[3 * p + 2] - bz) * sz));
        unsigned m = (p1b2(cz) << 2) | (p1b2(cy) << 1) | p1b2(cx);
        sk[p] = ((unsigned long long)m << 14) | (unsigned)p;
    }
    __syncthreads();

    // ---- bitonic sort (unique keys: idx in low bits) ----
    for (int k = 2; k <= N; k <<= 1) {
        for (int jj = k >> 1; jj > 0; jj >>= 1) {
            for (int q = t; q < N / 2; q += BT) {
                int i = ((q & ~(jj - 1)) << 1) | (q & (jj - 1));
                int pr = i | jj;
                unsigned long long a = sk[i], c = sk[pr];
                bool asc = ((i & k) == 0);
                if ((a > c) == asc) { sk[i] = c; sk[pr] = a; }
            }
            __syncthreads();
        }
    }

    // ---- permuted outputs ----
    for (int s = t; s < N; s += BT) {
        unsigned p = (unsigned)(sk[s] & 0x3FFFu);
        gidx[s] = p;
        gx[s] = xb[3 * p];
        gy[s] = xb[3 * p + 1];
        gz[s] = xb[3 * p + 2];
    }
    __threadfence_block();
    __syncthreads();

    // ---- per-16-point cluster stats: centroid + inflated radius ----
    // wave handles 4 clusters (16 lanes each); reduce within 16-lane groups.
    for (int cb = w * 4; cb < G; cb += 32) {
        int c = cb + (lane >> 4);
        int slot = c * 16 + (lane & 15);
        float x = gx[slot], y = gy[slot], z = gz[slot];
        float sxx = x, syy = y, szz = z;
#pragma unroll
        for (int m = 1; m < 16; m <<= 1) {
            sxx += __shfl_xor(sxx, m);
            syy += __shfl_xor(syy, m);
            szz += __shfl_xor(szz, m);
        }
        float ccx = sxx * (1.0f / 16.0f), ccy = syy * (1.0f / 16.0f), ccz = szz * (1.0f / 16.0f);
        float dx = x - ccx, dy = y - ccy, dz = z - ccz;
        float d2 = dx * dx + dy * dy + dz * dz;
#pragma unroll
        for (int m = 1; m < 16; m <<= 1) d2 = fmaxf(d2, __shfl_xor(d2, m));
        if ((lane & 15) == 0)
            gstats[c] = make_float4(ccx, ccy, ccz, sqrtf(d2) * 1.00001f + 1e-6f);
    }
}

// ---------------------------------------------------------------------------
// fps_lane<N,BT>: exact FPS, lane-granular cluster pruning.  Thread t owns
// ONE 16-point Morton cluster; coords/dd/~origidx/stats all in REGISTERS
// (~104 VGPR; BT=1024 block forces 4 waves/SIMD -> 128-VGPR cap, fits).
// Per step:
//   - per-lane bound test (pure VALU, no LDS, no branch ladder)
//   - flagged lanes update their 16 points via exec-mask divergence;
//     per-cluster max = lane-local u64 max chain (NO shuffles).  Contiguous
//     Morton ownership concentrates flagged lanes in 1-2 waves; other waves
//     pay only the bound test.
//   - one 64-lane butterfly over lane keys, lane0 -> LDS (parity dbuf),
//     ONE barrier, NW-key reduce, winner coords from original xyz.
// Exactness: skip iff (sqrt(d2c)*(1-1e-5)-rad)^2*(1-2e-5) >= cmax, margins
// >> fp32 slop => every skipped point has d_ref >= dd => fminf is identity.
// Key = dd_bits<<32 | ~origidx: max == furthest, ties -> lowest ORIGINAL
// index (jnp argmax first-max).  dd update uses exact jnp rounding (plain
// mul/add via __fmul_rn/__fadd_rn -- no fma contraction -- and fminf).
// ---------------------------------------------------------------------------
template<int N, int BT>
__global__ __launch_bounds__(BT)
void fps_lane(const float* __restrict__ xyz,
              const float* __restrict__ gx, const float* __restrict__ gy,
              const float* __restrict__ gz, const unsigned* __restrict__ gidx,
              const float4* __restrict__ gstats,
              int npoint, float* __restrict__ query)
{
    constexpr int NW = BT / 64;
    static_assert(N == BT * 16, "one 16-pt cluster per thread");
    __shared__ unsigned long long s_wkey[2][NW];

    const int b = blockIdx.x;
    const int t = threadIdx.x;
    const int lane = t & 63, w = t >> 6;
    const float* xb = xyz + (size_t)b * N * 3;
    const int base = t * 16;

    const float*    bgx = gx   + (size_t)b * N + base;
    const float*    bgy = gy   + (size_t)b * N + base;
    const float*    bgz = gz   + (size_t)b * N + base;
    const unsigned* bgi = gidx + (size_t)b * N + base;

    float px[16], py[16], pz[16], dd[16];
    unsigned nio[16];                         // ~origidx per point
#pragma unroll
    for (int i = 0; i < 4; ++i) {
        float4 vx = *(const float4*)(bgx + 4 * i);
        float4 vy = *(const float4*)(bgy + 4 * i);
        float4 vz = *(const float4*)(bgz + 4 * i);
        uint4  vi = *(const uint4*)(bgi + 4 * i);
        px[4*i+0] = vx.x; px[4*i+1] = vx.y; px[4*i+2] = vx.z; px[4*i+3] = vx.w;
        py[4*i+0] = vy.x; py[4*i+1] = vy.y; py[4*i+2] = vy.z; py[4*i+3] = vy.w;
        pz[4*i+0] = vz.x; pz[4*i+1] = vz.y; pz[4*i+2] = vz.z; pz[4*i+3] = vz.w;
        nio[4*i+0] = ~vi.x; nio[4*i+1] = ~vi.y; nio[4*i+2] = ~vi.z; nio[4*i+3] = ~vi.w;
        dd[4*i+0] = 1e10f; dd[4*i+1] = 1e10f; dd[4*i+2] = 1e10f; dd[4*i+3] = 1e10f;
    }
    const float4 cs = gstats[(size_t)b * (N / 16) + t];   // centroid + radius, regs

    float cx = xb[0], cy = xb[1], cz = xb[2];
    if (t == 0) {
        float* q = query + (size_t)b * npoint * 3;
        q[0] = cx; q[1] = cy; q[2] = cz;
    }
    // cluster key; high word doubles as prune bound cmax.  Step 1 always
    // flags (cmax=1e10 unbeatable), so this gets refreshed immediately.
    unsigned long long key = ((unsigned long long)__float_as_uint(1e10f) << 32);

    for (int step = 1; step < npoint; ++step) {
        const int buf = step & 1;
        // ---- per-lane bound test (registers only) ----
        float ddx = cs.x - cx, ddy = cs.y - cy, ddz = cs.z - cz;
        float d2c = ddx * ddx + ddy * ddy + ddz * ddz;
        float cmax = __uint_as_float((unsigned)(key >> 32));
        float Dlb = sqrtf(d2c) * 0.99999f - cs.w;
        bool flag = !(Dlb > 0.0f && Dlb * Dlb * 0.99998f >= cmax);
        // ---- divergent update of the 16 owned points ----
        if (flag) {
            unsigned long long nk = 0;        // any kp > 0
#pragma unroll
            for (int p = 0; p < 16; ++p) {
                float dx = px[p] - cx, dy = py[p] - cy, dz = pz[p] - cz;
                float d = __fmul_rn(dx, dx);
                d = __fadd_rn(d, __fmul_rn(dy, dy));
                d = __fadd_rn(d, __fmul_rn(dz, dz));
                float nd = fminf(dd[p], d);
                dd[p] = nd;
                unsigned long long kp =
                    ((unsigned long long)__float_as_uint(nd) << 32) | nio[p];
                nk = (kp > nk) ? kp : nk;
            }
            key = nk;
        }
        // ---- wave reduce over 64 lane keys ----
        unsigned long long k = key;
#pragma unroll
        for (int m = 1; m < 64; m <<= 1) {
            unsigned long long o = __shfl_xor(k, m);
            k = (o > k) ? o : k;
        }
        if (lane == 0) s_wkey[buf][w] = k;
        __syncthreads();
        // ---- block winner: NW keys, broadcast-friendly reads ----
        unsigned long long gk = s_wkey[buf][lane & (NW - 1)];
#pragma unroll
        for (int m = 1; m < NW; m <<= 1) {
            unsigned long long o = __shfl_xor(gk, m);
            gk = (o > gk) ? o : gk;
        }
        unsigned widx = ~(unsigned)gk;        // original index, block-uniform
        const float* wp = xb + (size_t)widx * 3;
        cx = wp[0]; cy = wp[1]; cz = wp[2];   // broadcast, exact original bits
        if (t == 0) {
            float* q = query + ((size_t)b * npoint + step) * 3;
            q[0] = cx; q[1] = cy; q[2] = cz;
        }
    }
}

// ---------------------------------------------------------------------------
// FPS brute force (stages 2-3, small N): coords in LDS, dd in registers.
// ---------------------------------------------------------------------------
template<int PPT, int BT, int WPE>
__global__ __launch_bounds__(BT)
__attribute__((amdgpu_waves_per_eu(WPE, WPE)))
void fps_gen(const float* __restrict__ xyz, int npoint, float* __restrict__ query)
{
    const int N = PPT * BT;
    constexpr int NW = BT / 64;
    __shared__ float4 s_p[PPT * BT];
    __shared__ unsigned long long s_wkey[2][NW];

    const int b = blockIdx.x;
    const int t = threadIdx.x;
    const int lane = t & 63;
    const int wid  = t >> 6;
    const float* xb = xyz + (size_t)b * N * 3;

    float dd[PPT];
#pragma unroll
    for (int i = 0; i < PPT; ++i) {
        int p = i * BT + t;
        const float* pp = xb + (size_t)p * 3;
        s_p[p] = make_float4(pp[0], pp[1], pp[2], 0.0f);
        dd[i] = 1e10f;
    }

    float cx = xb[0], cy = xb[1], cz = xb[2];
    if (t == 0) {
        float* q = query + (size_t)b * npoint * 3;
        q[0] = cx; q[1] = cy; q[2] = cz;
    }

    for (int step = 1; step < npoint; ++step) {
        const int buf = step & 1;
        float bd = -1.0f;
        int bslot = 0;
#pragma unroll
        for (int i = 0; i < PPT; ++i) {
            const float4 v = s_p[i * BT + t];
            float dx = v.x - cx, dy = v.y - cy, dz = v.z - cz;
            float d = __fmul_rn(dx, dx);
            d = __fadd_rn(d, __fmul_rn(dy, dy));
            d = __fadd_rn(d, __fmul_rn(dz, dz));
            float nd = fminf(dd[i], d);
            dd[i] = nd;
            bool g = nd > bd;
            bd    = g ? nd : bd;
            bslot = g ? i : bslot;
        }
        int bidx = bslot * BT + t;
        unsigned long long key =
            ((unsigned long long)__float_as_uint(bd) << 32) | (unsigned int)(~bidx);
#pragma unroll
        for (int m = 1; m < 64; m <<= 1) {
            unsigned long long o = __shfl_xor(key, m);
            key = (o > key) ? o : key;
        }
        if (lane == 0) s_wkey[buf][wid] = key;
        __syncthreads();
        unsigned long long v[NW];
#pragma unroll
        for (int w = 0; w < NW; ++w) v[w] = s_wkey[buf][w];
#pragma unroll
        for (int s = NW / 2; s > 0; s >>= 1)
#pragma unroll
            for (int w = 0; w < NW / 2; ++w)
                if (w < s) v[w] = (v[w + s] > v[w]) ? v[w + s] : v[w];
        unsigned int widx = ~(unsigned int)v[0];
        const float* wp = xb + (size_t)widx * 3;
        cx = wp[0]; cy = wp[1]; cz = wp[2];
        if (t == 0) {
            float* q = query + ((size_t)b * npoint + step) * 3;
            q[0] = cx; q[1] = cy; q[2] = cz;
        }
    }
}

// ---------------------------------------------------------------------------
// Ball query: one wave per query point, exact fp32 rounding (no fma).
// ---------------------------------------------------------------------------
__global__ void ballquery_kernel(const float* __restrict__ support,
                                 const float* __restrict__ query,
                                 int N, int Q, float r2,
                                 int* __restrict__ nbr)
{
    int gw   = (blockIdx.x * blockDim.x + threadIdx.x) >> 6;
    int lane = threadIdx.x & 63;
    if (gw >= NBATCH * Q) return;
    int b = gw / Q;
    int q = gw - b * Q;

    const float* sb = support + (size_t)b * N * 3;
    const float* qp = query + ((size_t)b * Q + q) * 3;
    float qx = qp[0], qy = qp[1], qz = qp[2];
    int* out = nbr + ((size_t)b * Q + q) * NSAMPLE;

    int cnt = 0, first = 0;
    for (int base = 0; base < N; base += 64) {
        int j = base + lane;
        float dx = __fsub_rn(sb[j * 3 + 0], qx);
        float dy = __fsub_rn(sb[j * 3 + 1], qy);
        float dz = __fsub_rn(sb[j * 3 + 2], qz);
        float d2 = __fmul_rn(dx, dx);
        d2 = __fadd_rn(d2, __fmul_rn(dy, dy));
        d2 = __fadd_rn(d2, __fmul_rn(dz, dz));
        bool inr = d2 < r2;
        unsigned long long mask = __ballot(inr);
        if (mask) {
            if (cnt == 0) first = base + (int)__builtin_ctzll(mask);
            if (inr) {
                int pos = cnt + (int)__popcll(mask & ((1ull << lane) - 1ull));
                if (pos < NSAMPLE) out[pos] = j;
            }
            cnt += (int)__popcll(mask);
            if (cnt >= NSAMPLE) break;
        }
    }
    for (int pos = cnt + lane; pos < NSAMPLE; pos += 64) out[pos] = first;
}

// ---------------------------------------------------------------------------
// Build F0 [3+C, Q*32] for one batch.
// ---------------------------------------------------------------------------
__global__ void gather_kernel(const float* __restrict__ support,
                              const float* __restrict__ query,
                              const int* __restrict__ nbr,
                              const float* __restrict__ feats,
                              int N, int Q, int C, int b,
                              float* __restrict__ F0)
{
    int n = blockIdx.x * blockDim.x + threadIdx.x;
    int Nn = Q * NSAMPLE;
    if (n >= Nn) return;
    int q = n >> 5, s = n & 31;
    int j = nbr[((size_t)b * Q + q) * NSAMPLE + s];
    const float* sp = support + ((size_t)b * N + j) * 3;
    const float* qp = query + ((size_t)b * Q + q) * 3;
    size_t NnS = (size_t)Nn;
    F0[n]           = sp[0] - qp[0];
    F0[NnS + n]     = sp[1] - qp[1];
    F0[2 * NnS + n] = sp[2] - qp[2];
    const float* fb = feats + (size_t)b * C * N;
    float* Fo = F0 + 3 * NnS + n;
    for (int c = 0; c < C; ++c) Fo[(size_t)c * NnS] = fb[(size_t)c * N + j];
}

// ---------------------------------------------------------------------------
// fp32 tiled GEMM with fused ReLU (and max-pool epilogue when POOL).
// ---------------------------------------------------------------------------
template<bool POOL>
__global__ __launch_bounds__(256)
void gemm_relu(const float* __restrict__ W, const float* __restrict__ bias,
               const float* __restrict__ F, float* __restrict__ Out,
               int M, int K, int Nn, int b)
{
    __shared__ float Ws[16][64];
    __shared__ float Fs[16][68];

    const int n0 = blockIdx.x * 64;
    const int m0 = blockIdx.y * 64;
    const int tid = threadIdx.x;
    const int tx = tid & 15, ty = tid >> 4;

    float acc[4][4] = {};

    const int wm = tid >> 2;
    const int wk = (tid & 3) * 4;
    const int fk = tid >> 4;
    const int fn = (tid & 15) * 4;

    for (int k0 = 0; k0 < K; k0 += 16) {
#pragma unroll
        for (int j = 0; j < 4; ++j) {
            int kk = wk + j;
            int kg = k0 + kk;
            Ws[kk][wm] = (kg < K) ? W[(size_t)(m0 + wm) * K + kg] : 0.0f;
        }
        {
            int kg = k0 + fk;
            float4 v = make_float4(0.f, 0.f, 0.f, 0.f);
            if (kg < K) v = *(const float4*)(F + (size_t)kg * Nn + n0 + fn);
            *(float4*)&Fs[fk][fn] = v;
        }
        __syncthreads();
#pragma unroll
        for (int kk = 0; kk < 16; ++kk) {
            float av[4], bv[4];
            *(float4*)av = *(const float4*)&Ws[kk][ty * 4];
            *(float4*)bv = *(const float4*)&Fs[kk][tx * 4];
#pragma unroll
            for (int i = 0; i < 4; ++i)
#pragma unroll
                for (int j = 0; j < 4; ++j)
                    acc[i][j] = fmaf(av[i], bv[j], acc[i][j]);
        }
        __syncthreads();
    }

    if constexpr (!POOL) {
#pragma unroll
        for (int i = 0; i < 4; ++i) {
            int m = m0 + ty * 4 + i;
            float bvs = bias[m];
            float4 r;
            r.x = fmaxf(acc[i][0] + bvs, 0.0f);
            r.y = fmaxf(acc[i][1] + bvs, 0.0f);
            r.z = fmaxf(acc[i][2] + bvs, 0.0f);
            r.w = fmaxf(acc[i][3] + bvs, 0.0f);
            *(float4*)(Out + (size_t)m * Nn + n0 + tx * 4) = r;
        }
    } else {
        __shared__ float Cs[64][65];
#pragma unroll
        for (int i = 0; i < 4; ++i) {
            int mr = ty * 4 + i;
            float bvs = bias[m0 + mr];
#pragma unroll
            for (int j = 0; j < 4; ++j)
                Cs[mr][tx * 4 + j] = fmaxf(acc[i][j] + bvs, 0.0f);
        }
        __syncthreads();
        if (tid < 128) {
            int r = tid >> 1, g = tid & 1;
            float mx = Cs[r][g * 32];
            for (int c = 1; c < 32; ++c) mx = fmaxf(mx, Cs[r][g * 32 + c]);
            int Qn = Nn >> 5;
            Out[((size_t)b * M + m0 + r) * Qn + (n0 >> 5) + g] = mx;
        }
    }
}

// ---------------------------------------------------------------------------
extern "C" void kernel_launch(void* const* d_in, const int* in_sizes, int n_in,
                              void* d_out, int out_size, void* d_ws, size_t ws_size,
                              hipStream_t stream)
{
    (void)in_sizes; (void)n_in; (void)out_size; (void)ws_size;
    const float* xyz = (const float*)d_in[0];
    const float* W[4][3]; const float* Bi[4][3];
    for (int k = 0; k < 4; ++k)
        for (int l = 0; l < 3; ++l) {
            W[k][l]  = (const float*)d_in[1 + k * 6 + l * 2];
            Bi[k][l] = (const float*)d_in[2 + k * 6 + l * 2];
        }
    float* out = (float*)d_out;

    uintptr_t cur = (uintptr_t)d_ws;
    auto alloc = [&](size_t bytes) -> void* {
        void* p = (void*)cur;
        cur += (bytes + 255) & ~(size_t)255;
        return p;
    };
    float* xyzT = (float*)alloc((size_t)NBATCH * 3 * 16384 * sizeof(float));
    float* qA   = (float*)alloc((size_t)NBATCH * 4096 * 3 * sizeof(float));
    float* qB   = (float*)alloc((size_t)NBATCH * 4096 * 3 * sizeof(float));
    int*   nbr  = (int*)  alloc((size_t)NBATCH * 4096 * NSAMPLE * sizeof(int));
    float* f0   = (float*)alloc((size_t)NBATCH * 128 * 4096 * sizeof(float));
    float* f1   = (float*)alloc((size_t)NBATCH * 256 * 1024 * sizeof(float));
    float* f2   = (float*)alloc((size_t)NBATCH * 512 * 256 * sizeof(float));
    float* X = (float*)alloc((size_t)8388608 * sizeof(float));
    float* Y = (float*)alloc((size_t)8388608 * sizeof(float));
    // cluster-FPS buffers (stage 0: N=16384 -> G=1024; stage 1: N=4096 -> G=256)
    float*    c0x = (float*)   alloc((size_t)NBATCH * 16384 * sizeof(float));
    float*    c0y = (float*)   alloc((size_t)NBATCH * 16384 * sizeof(float));
    float*    c0z = (float*)   alloc((size_t)NBATCH * 16384 * sizeof(float));
    unsigned* c0i = (unsigned*)alloc((size_t)NBATCH * 16384 * sizeof(unsigned));
    float4*   c0s = (float4*)  alloc((size_t)NBATCH * 1024 * sizeof(float4));
    float*    c1x = (float*)   alloc((size_t)NBATCH * 4096 * sizeof(float));
    float*    c1y = (float*)   alloc((size_t)NBATCH * 4096 * sizeof(float));
    float*    c1z = (float*)   alloc((size_t)NBATCH * 4096 * sizeof(float));
    unsigned* c1i = (unsigned*)alloc((size_t)NBATCH * 4096 * sizeof(unsigned));
    float4*   c1s = (float4*)  alloc((size_t)NBATCH * 256 * sizeof(float4));

    xyzT_kernel<<<(NBATCH * 16384 + 255) / 256, 256, 0, stream>>>(xyz, xyzT, 16384);

    struct StageP { int N, Q, Cprev, c1, c2, c3; double r; };
    const StageP st[4] = {
        {16384, 4096,   3,   64,  64,  128, 0.1},
        { 4096, 1024, 128,  128, 128,  256, 0.2},
        { 1024,  256, 256,  256, 256,  512, 0.4},
        {  256,   64, 512,  512, 512, 1024, 0.8},
    };
    const float* support   = xyz;
    const float* featsPrev = xyzT;
    float* qbuf[2]     = {qA, qB};
    float* featsOut[4] = {f0, f1, f2, out};

    for (int k = 0; k < 4; ++k) {
        const StageP& s = st[k];
        float* qcur = qbuf[k & 1];
        if (k == 0) {
            cluster_build<16384><<<NBATCH, 512, 0, stream>>>(support, c0x, c0y, c0z, c0i, c0s);
            fps_lane<16384, 1024><<<NBATCH, 1024, 0, stream>>>(
                support, c0x, c0y, c0z, c0i, c0s, s.Q, qcur);
        } else if (k == 1) {
            cluster_build<4096><<<NBATCH, 512, 0, stream>>>(support, c1x, c1y, c1z, c1i, c1s);
            fps_lane<4096, 256><<<NBATCH, 256, 0, stream>>>(
                support, c1x, c1y, c1z, c1i, c1s, s.Q, qcur);
        } else if (k == 2) {
            fps_gen<2, 512, 2><<<NBATCH, 512, 0, stream>>>(support, s.Q, qcur);
        } else {
            fps_gen<1, 256, 1><<<NBATCH, 256, 0, stream>>>(support, s.Q, qcur);
        }

        float r2 = (float)(s.r * s.r);
        ballquery_kernel<<<(NBATCH * s.Q) / 4, 256, 0, stream>>>(support, qcur, s.N, s.Q, r2, nbr);

        int K0 = 3 + s.Cprev;
        int Nn = s.Q * NSAMPLE;
        for (int b = 0; b < NBATCH; ++b) {
            gather_kernel<<<(Nn + 255) / 256, 256, 0, stream>>>(
                support, qcur, nbr, featsPrev, s.N, s.Q, s.Cprev, b, X);
            gemm_relu<false><<<dim3(Nn / 64, s.c1 / 64, 1), 256, 0, stream>>>(
                W[k][0], Bi[k][0], X, Y, s.c1, K0, Nn, 0);
            gemm_relu<false><<<dim3(Nn / 64, s.c2 / 64, 1), 256, 0, stream>>>(
                W[k][1], Bi[k][1], Y, X, s.c2, s.c1, Nn, 0);
            gemm_relu<true><<<dim3(Nn / 64, s.c3 / 64, 1), 256, 0, stream>>>(
                W[k][2], Bi[k][2], X, featsOut[k], s.c3, s.c2, Nn, b);
        }
        support   = qcur;
        featsPrev = featsOut[k];
    }
}